// Round 9
// baseline (154.622 us; speedup 1.0000x reference)
//
#include <hip/hip_runtime.h>
#include <math.h>

#define NPATCH 196
#define QROWS  204   // 196 + 8 pad rows so the depth-7 prefetch ring never goes OOB

typedef unsigned short ushort_t;

// ---- fast math helpers ----
__device__ __forceinline__ float fast_rcp(float x) { return __builtin_amdgcn_rcpf(x); }

// ---- bf16 pack/unpack ----
__device__ __forceinline__ ushort_t f2bf(float f) {
    unsigned u = __float_as_uint(f);
    u += 0x7FFFu + ((u >> 16) & 1u);
    return (ushort_t)(u >> 16);
}
__device__ __forceinline__ float bflo(unsigned v) { return __uint_as_float(v << 16); }          // low bf16 of dword
__device__ __forceinline__ float bfhi(unsigned v) { return __uint_as_float(v & 0xFFFF0000u); }  // high bf16 of dword

// ---- DPP cross-lane (VALU latency, no LDS) ----
template<int CTRL>
__device__ __forceinline__ int dpp_i(int x) {
    return __builtin_amdgcn_update_dpp(x, x, CTRL, 0xF, 0xF, true);
}
template<int CTRL>
__device__ __forceinline__ float dpp_f(float x) {
    return __int_as_float(dpp_i<CTRL>(__float_as_int(x)));
}
#define QP_BCAST0 0x00
#define QP_BCAST1 0x55
#define QP_BCAST2 0xAA
#define QP_BCAST3 0xFF
#define ROR4      0x124   // row_ror:4 (16-lane row rotate; absolute source probed at runtime)
#define ROR8      0x128
#define ROR12     0x12C

// ---------------------------------------------------------------------------
// Kernel 1: quanv (unchanged from R4/R5/R8 for attribution).
// ---------------------------------------------------------------------------
#define SPB  16
#define ROWP 788

__global__ __launch_bounds__(256) void quanv_kernel(const float* __restrict__ x,
                                                    const float* __restrict__ rl,
                                                    ushort_t* __restrict__ qfeat, int B)
{
    __shared__ float tile[SPB][ROWP];
    const int tid = threadIdx.x;
    const int b0  = blockIdx.x * SPB;

#pragma unroll 4
    for (int r = 0; r < SPB; ++r) {
        if (tid < 196) {
            ((float4*)&tile[r][0])[tid] =
                ((const float4*)(x + (size_t)(b0 + r) * 784))[tid];
        }
    }
    __syncthreads();

    float rs[4], rc[4];
#pragma unroll
    for (int w = 0; w < 4; ++w) __sincosf(rl[w] * 0.5f, &rs[w], &rc[w]);

    const int s  = tid & 15;
    const int tg = tid >> 4;
    const float* row = &tile[s][0];

    for (int t = tg; t < NPATCH; t += 16) {
        int i = t / 14, j = t - i * 14;
        int o = i * 56 + j * 2;
        float a[4] = { row[o], row[o + 1], row[o + 28], row[o + 29] };

        float cw[4], sw[4];
#pragma unroll
        for (int w = 0; w < 4; ++w) __sincosf(a[w] * 0.5f, &sw[w], &cw[w]);

        float amp[16];
#pragma unroll
        for (int idx = 0; idx < 16; ++idx) {
            float v = ((idx & 8) ? sw[0] : cw[0]) * ((idx & 4) ? sw[1] : cw[1]);
            v *= ((idx & 2) ? sw[2] : cw[2]);
            v *= ((idx & 1) ? sw[3] : cw[3]);
            amp[idx] = v;
        }

#pragma unroll
        for (int w = 0; w < 4; ++w) {
            const int mask = 8 >> w;
#pragma unroll
            for (int idx = 0; idx < 16; ++idx) {
                if (!(idx & mask)) {
                    float a0 = amp[idx], a1 = amp[idx | mask];
                    amp[idx]        = rc[w] * a0 - rs[w] * a1;
                    amp[idx | mask] = rs[w] * a0 + rc[w] * a1;
                }
            }
            const int tmask = 8 >> ((w + 1) & 3);
#pragma unroll
            for (int idx = 0; idx < 16; ++idx) {
                if ((idx & mask) && !(idx & tmask)) {
                    float tmp = amp[idx];
                    amp[idx] = amp[idx | tmask];
                    amp[idx | tmask] = tmp;
                }
            }
        }

        float p[16];
#pragma unroll
        for (int idx = 0; idx < 16; ++idx) p[idx] = amp[idx] * amp[idx];
        float z0 = 0.f, z1 = 0.f, z2 = 0.f, z3 = 0.f;
#pragma unroll
        for (int idx = 0; idx < 16; ++idx) {
            z0 += (idx & 8) ? -p[idx] : p[idx];
            z1 += (idx & 4) ? -p[idx] : p[idx];
            z2 += (idx & 2) ? -p[idx] : p[idx];
            z3 += (idx & 1) ? -p[idx] : p[idx];
        }

        ushort4 outv;
        outv.x = f2bf(z0); outv.y = f2bf(z1); outv.z = f2bf(z2); outv.w = f2bf(z3);
        *(ushort4*)(qfeat + ((size_t)t * B + (b0 + s)) * 4) = outv;
    }
}

// ---------------------------------------------------------------------------
// Kernel 2: LSTM scan, chain-shortened. Layout as R8 (16 lanes per sample
// pair, lane16 = u*4+k, 2 samples/thread). The h-recurrence chain is the
// measured floor (~730 cyc/step in R5/R8) — this version removes ALL
// transcendentals from the chain:
//   angle = a + d; a = Wx·x+b (off-chain, real __sincosf, hides in stalls);
//   d = Wh·h (on-chain, |d|<~2) -> sin_d/cos_d by Taylor polys;
//   cos(a+d) = ca*cos_d - sa*sin_d;
//   gates: z in [-1,1] (product of cosines) -> deg-9 odd poly
//     (sigmoid: Taylor, err 2e-5; tanh: endpoint-corrected, err <=4e-4),
//     per-lane coefficients, no divergence;
//   tanh(cx): |cx|<=2.07 (contraction) -> Pade(3,3), err <=1e-4, single rcp.
// ---------------------------------------------------------------------------
__global__ __launch_bounds__(256) void lstm_kernel(const ushort_t* __restrict__ qfeat,
                                                   const float* __restrict__ lin_W,
                                                   const float* __restrict__ lin_b,
                                                   const float* __restrict__ qtheta,
                                                   float* __restrict__ sums, int B)
{
    const int tid = threadIdx.x;
    const int gid = blockIdx.x * 256 + tid;
    const int pr  = gid >> 4;           // sample-pair index, 0 .. B/2-1
    const int u   = (tid >> 2) & 3;
    const int k   = tid & 3;
    const int Bh  = B >> 1;

    // --- direction probe: which absolute u arrives via each ror ---
    const int j1 = dpp_i<ROR4>(u);
    const int j2 = dpp_i<ROR8>(u);
    const int j3 = dpp_i<ROR12>(u);

    // --- per-lane weights: column u of circuit k ---
    const float Wx0 = lin_W[(k * 8 + 0) * 4 + u];
    const float Wx1 = lin_W[(k * 8 + 1) * 4 + u];
    const float Wx2 = lin_W[(k * 8 + 2) * 4 + u];
    const float Wx3 = lin_W[(k * 8 + 3) * 4 + u];
    const float Wh0 = lin_W[(k * 8 + 4 + u)  * 4 + u];
    const float Wh1 = lin_W[(k * 8 + 4 + j1) * 4 + u];
    const float Wh2 = lin_W[(k * 8 + 4 + j2) * 4 + u];
    const float Wh3 = lin_W[(k * 8 + 4 + j3) * 4 + u];
    const float bt  = lin_b[k * 4 + u] + qtheta[k * 4 + u];

    // --- product-subset masks: S_0={1,2,3}, S_1={0,1}, S_2={0,1,2}, S_3=all ---
    auto in_set = [](int j, int uu) {
        return (uu == 0) ? (j != 0) : (uu == 1) ? (j <= 1) : (uu == 2) ? (j <= 2) : true;
    };
    const bool inc0 = in_set(u,  u);
    const bool inc1 = in_set(j1, u);
    const bool inc2 = in_set(j2, u);
    const bool inc3 = in_set(j3, u);

    // --- gate poly coefficients: gate(z) = GA + z*(G0 + zz*(G1 + zz*(G2 + zz*(G3 + zz*G4))))
    //     k==2: tanh (deg-9, endpoint-corrected) ; else sigmoid (deg-9 Taylor)
    const bool  tk = (k == 2);
    const float GA = tk ? 0.0f          : 0.5f;
    const float G0 = tk ? 1.0f          : 0.25f;
    const float G1 = tk ? -0.33333333f  : -2.0833333e-2f;   // -1/3          | -1/48
    const float G2 = tk ? 0.13333333f   : 2.0833333e-3f;    //  2/15         |  1/480
    const float G3 = tk ? -5.3968254e-2f: -2.1081349e-4f;   // -17/315       | -17/80640
    const float G4 = tk ? 1.5567200e-2f : 2.1356922e-5f;    // corrected     |  31/1451520

    const uint4* qp = (const uint4*)qfeat;    // 16 B = one t, one sample pair
    uint4 r0 = qp[(size_t)0 * Bh + pr];
    uint4 r1 = qp[(size_t)1 * Bh + pr];
    uint4 r2 = qp[(size_t)2 * Bh + pr];
    uint4 r3 = qp[(size_t)3 * Bh + pr];
    uint4 r4 = qp[(size_t)4 * Bh + pr];
    uint4 r5 = qp[(size_t)5 * Bh + pr];
    uint4 r6 = qp[(size_t)6 * Bh + pr];

    float cxa = 0.f, hxa = 0.f;   // sample A = 2*pr
    float cxb = 0.f, hxb = 0.f;   // sample B = 2*pr+1

    auto step = [&](uint4& buf, int tn) {
        float ax0 = bflo(buf.x), ax1 = bfhi(buf.x), ax2 = bflo(buf.y), ax3 = bfhi(buf.y);
        float bx0 = bflo(buf.z), bx1 = bfhi(buf.z), bx2 = bflo(buf.w), bx3 = bfhi(buf.w);
        buf = qp[(size_t)tn * Bh + pr];          // prefetch 7 steps ahead

        // ---- OFF-CHAIN: x-part angle and its exact sin/cos ----
        float aa = fmaf(ax0, Wx0, fmaf(ax1, Wx1, fmaf(ax2, Wx2, fmaf(ax3, Wx3, bt))));
        float ab = fmaf(bx0, Wx0, fmaf(bx1, Wx1, fmaf(bx2, Wx2, fmaf(bx3, Wx3, bt))));
        float saa, caa, sab, cab;
        __sincosf(aa, &saa, &caa);
        __sincosf(ab, &sab, &cab);

        // ---- CHAIN: d = Wh·h ----
        float ha1 = dpp_f<ROR4>(hxa),  hb1 = dpp_f<ROR4>(hxb);
        float ha2 = dpp_f<ROR8>(hxa),  hb2 = dpp_f<ROR8>(hxb);
        float ha3 = dpp_f<ROR12>(hxa), hb3 = dpp_f<ROR12>(hxb);
        float da = fmaf(ha1, Wh1, hxa * Wh0) + fmaf(ha3, Wh3, ha2 * Wh2);
        float db = fmaf(hb1, Wh1, hxb * Wh0) + fmaf(hb3, Wh3, hb2 * Wh2);

        // sin/cos of small d (Taylor, |d| <~ 2)
        float qa = da * da, qb = db * db;
        float cda = fmaf(qa, fmaf(qa, fmaf(qa, fmaf(qa, 2.4801587e-5f, -1.3888889e-3f), 4.1666668e-2f), -0.5f), 1.0f);
        float cdb = fmaf(qb, fmaf(qb, fmaf(qb, fmaf(qb, 2.4801587e-5f, -1.3888889e-3f), 4.1666668e-2f), -0.5f), 1.0f);
        float sda = da * fmaf(qa, fmaf(qa, fmaf(qa, -1.9841270e-4f, 8.3333333e-3f), -0.16666667f), 1.0f);
        float sdb = db * fmaf(qb, fmaf(qb, fmaf(qb, -1.9841270e-4f, 8.3333333e-3f), -0.16666667f), 1.0f);

        // cos(a+d) = ca*cos_d - sa*sin_d
        float cva = fmaf(caa, cda, -(saa * sda));
        float cvb = fmaf(cab, cdb, -(sab * sdb));

        // subset products
        float ca1 = dpp_f<ROR4>(cva),  cb1 = dpp_f<ROR4>(cvb);
        float ca2 = dpp_f<ROR8>(cva),  cb2 = dpp_f<ROR8>(cvb);
        float ca3 = dpp_f<ROR12>(cva), cb3 = dpp_f<ROR12>(cvb);
        float za = ((inc0 ? cva : 1.0f) * (inc1 ? ca1 : 1.0f))
                 * ((inc2 ? ca2 : 1.0f) * (inc3 ? ca3 : 1.0f));
        float zb = ((inc0 ? cvb : 1.0f) * (inc1 ? cb1 : 1.0f))
                 * ((inc2 ? cb2 : 1.0f) * (inc3 ? cb3 : 1.0f));

        // gate nonlinearity (poly, no trans)
        float zza = za * za, zzb = zb * zb;
        float pa = fmaf(zza, fmaf(zza, fmaf(zza, fmaf(zza, G4, G3), G2), G1), G0);
        float pb = fmaf(zzb, fmaf(zzb, fmaf(zzb, fmaf(zzb, G4, G3), G2), G1), G0);
        float gva = fmaf(za, pa, GA);
        float gvb = fmaf(zb, pb, GA);

        // collect f,i,g,o across k (quad broadcast)
        float fa = dpp_f<QP_BCAST0>(gva), fb = dpp_f<QP_BCAST0>(gvb);
        float ia = dpp_f<QP_BCAST1>(gva), ib = dpp_f<QP_BCAST1>(gvb);
        float g_a = dpp_f<QP_BCAST2>(gva), g_b = dpp_f<QP_BCAST2>(gvb);
        float oa = dpp_f<QP_BCAST3>(gva), ob = dpp_f<QP_BCAST3>(gvb);

        cxa = fmaf(fa, cxa, ia * g_a);
        cxb = fmaf(fb, cxb, ib * g_b);

        // tanh(cx) via Pade(3,3): x(945+105x^2+x^4)/(945+420x^2+15x^4)
        float s2a = cxa * cxa, s2b = cxb * cxb;
        float na   = fmaf(s2a, s2a + 105.0f, 945.0f);
        float nb   = fmaf(s2b, s2b + 105.0f, 945.0f);
        float dena = fmaf(s2a, fmaf(s2a, 15.0f, 420.0f), 945.0f);
        float denb = fmaf(s2b, fmaf(s2b, 15.0f, 420.0f), 945.0f);
        hxa = (oa * cxa) * (na * fast_rcp(dena));
        hxb = (ob * cxb) * (nb * fast_rcp(denb));
    };

    for (int t = 0; t < NPATCH; t += 7) {
        step(r0, t + 7);
        step(r1, t + 8);
        step(r2, t + 9);
        step(r3, t + 10);
        step(r4, t + 11);
        step(r5, t + 12);
        step(r6, t + 13);   // pad rows 196..203 exist, loaded but never decoded
    }

    // batch-sum of final h
    float v = hxa + hxb;
    v += __shfl_xor(v, 16, 64);
    v += __shfl_xor(v, 32, 64);
    if ((tid & 63) < 16 && k == 0) atomicAdd(sums + u, v);
}

// ---------------------------------------------------------------------------
// Kernel 3: out[b] = prod_j cos(w_j) * prod_j cos(x[b][j]), w = sums/B
// ---------------------------------------------------------------------------
__global__ __launch_bounds__(256) void final_kernel(const float* __restrict__ x,
                                                    const float* __restrict__ sums,
                                                    float* __restrict__ out,
                                                    int B, float invB)
{
    int b = blockIdx.x * blockDim.x + threadIdx.x;
    if (b >= B) return;
    float P = cosf(sums[0] * invB) * cosf(sums[1] * invB) *
              cosf(sums[2] * invB) * cosf(sums[3] * invB);
    const float4 xi = *(const float4*)(x + (size_t)b * 784);
    out[b] = P * cosf(xi.x) * cosf(xi.y) * cosf(xi.z) * cosf(xi.w);
}

extern "C" void kernel_launch(void* const* d_in, const int* in_sizes, int n_in,
                              void* d_out, int out_size, void* d_ws, size_t ws_size,
                              hipStream_t stream)
{
    const float* x      = (const float*)d_in[0];
    const float* rl     = (const float*)d_in[1];
    const float* lin_W  = (const float*)d_in[2];
    const float* lin_b  = (const float*)d_in[3];
    const float* qtheta = (const float*)d_in[4];
    float* out = (float*)d_out;
    int B = in_sizes[0] / 784;

    float*    sums  = (float*)d_ws;                      // 4 floats
    ushort_t* qfeat = (ushort_t*)((char*)d_ws + 256);    // [QROWS][B][4] bf16

    hipMemsetAsync(sums, 0, 4 * sizeof(float), stream);

    quanv_kernel<<<B / SPB, 256, 0, stream>>>(x, rl, qfeat, B);

    // (B/2 pairs) * 16 lanes = B*8 threads
    lstm_kernel<<<(B * 8) / 256, 256, 0, stream>>>(qfeat, lin_W, lin_b, qtheta, sums, B);

    final_kernel<<<(B + 255) / 256, 256, 0, stream>>>(x, sums, out, B, 1.0f / (float)B);
}

// Round 13
// 144.242 us; speedup vs baseline: 1.0720x; 1.0720x over previous
//
#include <hip/hip_runtime.h>
#include <math.h>

#define NPATCH 196
#define TPAD   202   // pair stride 202*16B: 808 dwords % 32 banks = 8 -> the 4
                     // pairs of a wave read distinct bank groups (no conflict)

typedef unsigned short ushort_t;

// ---- fast math helpers ----
__device__ __forceinline__ float fast_rcp(float x) { return __builtin_amdgcn_rcpf(x); }

// ---- bf16 pack/unpack ----
__device__ __forceinline__ ushort_t f2bf(float f) {
    unsigned u = __float_as_uint(f);
    u += 0x7FFFu + ((u >> 16) & 1u);
    return (ushort_t)(u >> 16);
}
__device__ __forceinline__ float bflo(unsigned v) { return __uint_as_float(v << 16); }
__device__ __forceinline__ float bfhi(unsigned v) { return __uint_as_float(v & 0xFFFF0000u); }

// ---- DPP cross-lane (VALU latency, no LDS) ----
template<int CTRL>
__device__ __forceinline__ int dpp_i(int x) {
    return __builtin_amdgcn_update_dpp(x, x, CTRL, 0xF, 0xF, true);
}
template<int CTRL>
__device__ __forceinline__ float dpp_f(float x) {
    return __int_as_float(dpp_i<CTRL>(__float_as_int(x)));
}
#define QP_BCAST0 0x00
#define QP_BCAST1 0x55
#define QP_BCAST2 0xAA
#define QP_BCAST3 0xFF
#define ROR4      0x124   // row_ror:4 (absolute source u probed at runtime)
#define ROR8      0x128
#define ROR12     0x12C

// ---------------------------------------------------------------------------
// Fused kernel: block = 32 samples (16 pairs).
// Phase 1 (quanv): thread (sb=tid>>3, tsub=tid&7) simulates patches
//   t = tsub+8j of sample sb -> bf16x4 into LDS feat[pair][t][parity].
// Phase 2 (scan): R8's LSTM layout (16 lanes/pair, lane16 = u*4+k, two
//   samples per thread) reading features from LDS (1-deep prefetch;
//   ds latency ~120cyc << step, so compiler sinking can't hurt).
// No global qfeat: removes 6.5MB HBM write + 6.3MB fabric re-fetch that
// R8's scan stalled on (compiler sank the "7-deep" ring loads; VGPR=36
// proved the ring never lived in registers).
// ---------------------------------------------------------------------------
__global__ __launch_bounds__(256, 1) void fused_kernel(
        const float* __restrict__ x,
        const float* __restrict__ rl,
        const float* __restrict__ lin_W,
        const float* __restrict__ lin_b,
        const float* __restrict__ qtheta,
        float* __restrict__ sums, int B)
{
    __shared__ alignas(16) ushort_t feat[16][TPAD][8];   // 51.7 KB

    const int tid = threadIdx.x;

    // ================= phase 1: quanv =================
    {
        const int sb    = tid >> 3;              // sample-in-block 0..31
        const int tsub  = tid & 7;
        const int smp   = blockIdx.x * 32 + sb;
        const int pairb = sb >> 1;
        const int par   = sb & 1;

        float rs[4], rc[4];
#pragma unroll
        for (int w = 0; w < 4; ++w) __sincosf(rl[w] * 0.5f, &rs[w], &rc[w]);

        const float* row = x + (size_t)smp * 784;

        for (int jt = 0; jt < 25; ++jt) {
            int t = tsub + (jt << 3);
            if (t < NPATCH) {
                int i = t / 14, j = t - i * 14;
                int o = i * 56 + j * 2;
                float2 p01 = *(const float2*)(row + o);
                float2 p23 = *(const float2*)(row + o + 28);
                float a[4] = { p01.x, p01.y, p23.x, p23.y };

                float cw[4], sw[4];
#pragma unroll
                for (int w = 0; w < 4; ++w) __sincosf(a[w] * 0.5f, &sw[w], &cw[w]);

                float amp[16];
#pragma unroll
                for (int idx = 0; idx < 16; ++idx) {
                    float v = ((idx & 8) ? sw[0] : cw[0]) * ((idx & 4) ? sw[1] : cw[1]);
                    v *= ((idx & 2) ? sw[2] : cw[2]);
                    v *= ((idx & 1) ? sw[3] : cw[3]);
                    amp[idx] = v;
                }
#pragma unroll
                for (int w = 0; w < 4; ++w) {
                    const int mask = 8 >> w;
#pragma unroll
                    for (int idx = 0; idx < 16; ++idx) {
                        if (!(idx & mask)) {
                            float a0 = amp[idx], a1 = amp[idx | mask];
                            amp[idx]        = rc[w] * a0 - rs[w] * a1;
                            amp[idx | mask] = rs[w] * a0 + rc[w] * a1;
                        }
                    }
                    const int tmask = 8 >> ((w + 1) & 3);
#pragma unroll
                    for (int idx = 0; idx < 16; ++idx) {
                        if ((idx & mask) && !(idx & tmask)) {
                            float tmp = amp[idx];
                            amp[idx] = amp[idx | tmask];
                            amp[idx | tmask] = tmp;
                        }
                    }
                }
                float p[16];
#pragma unroll
                for (int idx = 0; idx < 16; ++idx) p[idx] = amp[idx] * amp[idx];
                float z0 = 0.f, z1 = 0.f, z2 = 0.f, z3 = 0.f;
#pragma unroll
                for (int idx = 0; idx < 16; ++idx) {
                    z0 += (idx & 8) ? -p[idx] : p[idx];
                    z1 += (idx & 4) ? -p[idx] : p[idx];
                    z2 += (idx & 2) ? -p[idx] : p[idx];
                    z3 += (idx & 1) ? -p[idx] : p[idx];
                }
                ushort4 ov;
                ov.x = f2bf(z0); ov.y = f2bf(z1); ov.z = f2bf(z2); ov.w = f2bf(z3);
                *(ushort4*)&feat[pairb][t][par * 4] = ov;
            }
        }
    }
    __syncthreads();

    // ================= phase 2: LSTM scan (R8 math) =================
    const int pr = tid >> 4;            // pair-in-block 0..15
    const int u  = (tid >> 2) & 3;
    const int k  = tid & 3;

    const int j1 = dpp_i<ROR4>(u);
    const int j2 = dpp_i<ROR8>(u);
    const int j3 = dpp_i<ROR12>(u);

    const float Wx0 = lin_W[(k * 8 + 0) * 4 + u];
    const float Wx1 = lin_W[(k * 8 + 1) * 4 + u];
    const float Wx2 = lin_W[(k * 8 + 2) * 4 + u];
    const float Wx3 = lin_W[(k * 8 + 3) * 4 + u];
    const float Wh0 = lin_W[(k * 8 + 4 + u)  * 4 + u];
    const float Wh1 = lin_W[(k * 8 + 4 + j1) * 4 + u];
    const float Wh2 = lin_W[(k * 8 + 4 + j2) * 4 + u];
    const float Wh3 = lin_W[(k * 8 + 4 + j3) * 4 + u];
    const float bt  = lin_b[k * 4 + u] + qtheta[k * 4 + u];

    auto in_set = [](int j, int uu) {
        return (uu == 0) ? (j != 0) : (uu == 1) ? (j <= 1) : (uu == 2) ? (j <= 2) : true;
    };
    const bool inc0 = in_set(u,  u);
    const bool inc1 = in_set(j1, u);
    const bool inc2 = in_set(j2, u);
    const bool inc3 = in_set(j3, u);

    const float mlt = (k == 2) ?  2.0f : -1.0f;
    const float ga  = (k == 2) ? -2.0f :  1.0f;
    const float gb  = (k == 2) ?  1.0f :  0.0f;

    float cxa = 0.f, hxa = 0.f;   // sample A = even
    float cxb = 0.f, hxb = 0.f;   // sample B = odd

    uint4 cur = *(const uint4*)&feat[pr][0][0];

#pragma unroll 4
    for (int t = 0; t < NPATCH; ++t) {
        uint4 nxt = *(const uint4*)&feat[pr][t + 1][0];   // t=195 reads pad row (never decoded)

        float ax0 = bflo(cur.x), ax1 = bfhi(cur.x), ax2 = bflo(cur.y), ax3 = bfhi(cur.y);
        float bx0 = bflo(cur.z), bx1 = bfhi(cur.z), bx2 = bflo(cur.w), bx3 = bfhi(cur.w);

        float ha1 = dpp_f<ROR4>(hxa),  hb1 = dpp_f<ROR4>(hxb);
        float ha2 = dpp_f<ROR8>(hxa),  hb2 = dpp_f<ROR8>(hxb);
        float ha3 = dpp_f<ROR12>(hxa), hb3 = dpp_f<ROR12>(hxb);

        float as0 = fmaf(ax0, Wx0, bt);
        float bs0 = fmaf(bx0, Wx0, bt);
        float as1 = ax1 * Wx1;
        float bs1 = bx1 * Wx1;
        as0 = fmaf(ax2, Wx2, as0);  bs0 = fmaf(bx2, Wx2, bs0);
        as1 = fmaf(ax3, Wx3, as1);  bs1 = fmaf(bx3, Wx3, bs1);
        as0 = fmaf(hxa, Wh0, as0);  bs0 = fmaf(hxb, Wh0, bs0);
        as1 = fmaf(ha1, Wh1, as1);  bs1 = fmaf(hb1, Wh1, bs1);
        as0 = fmaf(ha2, Wh2, as0);  bs0 = fmaf(hb2, Wh2, bs0);
        as1 = fmaf(ha3, Wh3, as1);  bs1 = fmaf(hb3, Wh3, bs1);
        float cva = __cosf(as0 + as1);
        float cvb = __cosf(bs0 + bs1);

        float ca1 = dpp_f<ROR4>(cva),  cb1 = dpp_f<ROR4>(cvb);
        float ca2 = dpp_f<ROR8>(cva),  cb2 = dpp_f<ROR8>(cvb);
        float ca3 = dpp_f<ROR12>(cva), cb3 = dpp_f<ROR12>(cvb);
        float za = ((inc0 ? cva : 1.0f) * (inc1 ? ca1 : 1.0f))
                 * ((inc2 ? ca2 : 1.0f) * (inc3 ? ca3 : 1.0f));
        float zb = ((inc0 ? cvb : 1.0f) * (inc1 ? cb1 : 1.0f))
                 * ((inc2 ? cb2 : 1.0f) * (inc3 ? cb3 : 1.0f));

        float ea  = __expf(za * mlt);
        float eb  = __expf(zb * mlt);
        float gva = fmaf(fast_rcp(1.0f + ea), ga, gb);
        float gvb = fmaf(fast_rcp(1.0f + eb), ga, gb);

        float fa = dpp_f<QP_BCAST0>(gva), fb = dpp_f<QP_BCAST0>(gvb);
        float ia = dpp_f<QP_BCAST1>(gva), ib = dpp_f<QP_BCAST1>(gvb);
        float g_a = dpp_f<QP_BCAST2>(gva), g_b = dpp_f<QP_BCAST2>(gvb);
        float oa = dpp_f<QP_BCAST3>(gva), ob = dpp_f<QP_BCAST3>(gvb);

        cxa = fmaf(fa, cxa, ia * g_a);
        cxb = fmaf(fb, cxb, ib * g_b);
        float ta = fmaf(-2.0f, fast_rcp(1.0f + __expf(2.0f * cxa)), 1.0f);
        float tb = fmaf(-2.0f, fast_rcp(1.0f + __expf(2.0f * cxb)), 1.0f);
        hxa = oa * ta;
        hxb = ob * tb;

        cur = nxt;
    }

    // batch-sum of final h
    float v = hxa + hxb;
    v += __shfl_xor(v, 16, 64);
    v += __shfl_xor(v, 32, 64);
    if ((tid & 63) < 16 && k == 0) atomicAdd(sums + u, v);
}

// ---------------------------------------------------------------------------
// Final: out[b] = prod_j cos(w_j) * prod_j cos(x[b][j]), w = sums/B
// ---------------------------------------------------------------------------
__global__ __launch_bounds__(256) void final_kernel(const float* __restrict__ x,
                                                    const float* __restrict__ sums,
                                                    float* __restrict__ out,
                                                    int B, float invB)
{
    int b = blockIdx.x * blockDim.x + threadIdx.x;
    if (b >= B) return;
    float P = cosf(sums[0] * invB) * cosf(sums[1] * invB) *
              cosf(sums[2] * invB) * cosf(sums[3] * invB);
    const float4 xi = *(const float4*)(x + (size_t)b * 784);
    out[b] = P * cosf(xi.x) * cosf(xi.y) * cosf(xi.z) * cosf(xi.w);
}

extern "C" void kernel_launch(void* const* d_in, const int* in_sizes, int n_in,
                              void* d_out, int out_size, void* d_ws, size_t ws_size,
                              hipStream_t stream)
{
    const float* x      = (const float*)d_in[0];
    const float* rl     = (const float*)d_in[1];
    const float* lin_W  = (const float*)d_in[2];
    const float* lin_b  = (const float*)d_in[3];
    const float* qtheta = (const float*)d_in[4];
    float* out = (float*)d_out;
    int B = in_sizes[0] / 784;

    float* sums = (float*)d_ws;   // 4 floats

    hipMemsetAsync(sums, 0, 4 * sizeof(float), stream);

    fused_kernel<<<B / 32, 256, 0, stream>>>(x, rl, lin_W, lin_b, qtheta, sums, B);

    final_kernel<<<(B + 255) / 256, 256, 0, stream>>>(x, sums, out, B, 1.0f / (float)B);
}